// Round 1
// baseline (209.582 us; speedup 1.0000x reference)
//
#include <hip/hip_runtime.h>

// GCNConv: out = A @ (X @ W)
//   X  [N=50000, D_IN=256]  fp32
//   W  [D_IN=256, D_OUT=128] fp32
//   A  unweighted CSR adjacency (row_pointers, column_index), deg=16 uniform
// Stage 1: Xp = X @ W  (dense GEMM, fp32, register-tiled)  -> d_ws
// Stage 2: out[i,:] = sum_{e in [rp[i],rp[i+1])} Xp[ci[e],:]  (SpMM gather-sum)

constexpr int D_IN  = 256;
constexpr int D_OUT = 128;
constexpr int BM = 64;
constexpr int BK = 32;

__global__ __launch_bounds__(256) void gemm_xw(const float* __restrict__ X,
                                               const float* __restrict__ W,
                                               float* __restrict__ Xp, int n) {
    __shared__ float As[BM][BK];      // 8 KB
    __shared__ float Bs[BK][D_OUT];   // 16 KB
    const int tid  = threadIdx.x;
    const int row0 = blockIdx.x * BM;
    const int tc = tid & 31;   // 32 column groups of 4 (covers 128 cols)
    const int tr = tid >> 5;   // 8 row groups of 8 (covers 64 rows)

    float acc[8][4];
#pragma unroll
    for (int i = 0; i < 8; ++i) {
        acc[i][0] = acc[i][1] = acc[i][2] = acc[i][3] = 0.f;
    }

    for (int k0 = 0; k0 < D_IN; k0 += BK) {
        // Stage A tile: 64x32 floats = 512 float4, 2 per thread, coalesced rows
#pragma unroll
        for (int i = 0; i < 2; ++i) {
            int f4 = tid + i * 256;
            int r  = f4 >> 3;      // 8 float4 per row of 32 floats
            int c4 = f4 & 7;
            float4 v = make_float4(0.f, 0.f, 0.f, 0.f);
            int row = row0 + r;
            if (row < n) v = *(const float4*)(X + (size_t)row * D_IN + k0 + c4 * 4);
            *(float4*)(&As[r][c4 * 4]) = v;
        }
        // Stage B tile: 32x128 floats = 1024 float4, 4 per thread, coalesced
#pragma unroll
        for (int i = 0; i < 4; ++i) {
            int f4 = tid + i * 256;
            int r  = f4 >> 5;      // 32 float4 per row of 128 floats
            int c4 = f4 & 31;
            *(float4*)(&Bs[r][c4 * 4]) =
                *(const float4*)(W + (size_t)(k0 + r) * D_OUT + c4 * 4);
        }
        __syncthreads();

#pragma unroll
        for (int k = 0; k < BK; ++k) {
            float4 b = *(const float4*)(&Bs[k][tc * 4]);   // ds_read_b128, contiguous
            float a[8];
#pragma unroll
            for (int i = 0; i < 8; ++i) a[i] = As[tr * 8 + i][k];  // wave-broadcast reads
#pragma unroll
            for (int i = 0; i < 8; ++i) {
                acc[i][0] += a[i] * b.x;
                acc[i][1] += a[i] * b.y;
                acc[i][2] += a[i] * b.z;
                acc[i][3] += a[i] * b.w;
            }
        }
        __syncthreads();
    }

#pragma unroll
    for (int i = 0; i < 8; ++i) {
        int row = row0 + tr * 8 + i;
        if (row < n)
            *(float4*)(Xp + (size_t)row * D_OUT + tc * 4) = *(float4*)(&acc[i][0]);
    }
}

// 32 lanes per node (lane covers 4 of 128 cols), 8 nodes per 256-thread block.
__global__ __launch_bounds__(256) void spmm_agg(const float* __restrict__ Xp,
                                                const int* __restrict__ rowp,
                                                const int* __restrict__ colx,
                                                float* __restrict__ out, int n) {
    const int node = blockIdx.x * 8 + (threadIdx.x >> 5);
    const int lane = threadIdx.x & 31;
    if (node >= n) return;
    const int e0 = rowp[node];
    const int e1 = rowp[node + 1];
    float4 acc = make_float4(0.f, 0.f, 0.f, 0.f);
    for (int e = e0; e < e1; ++e) {
        int c = colx[e];
        float4 v = *(const float4*)(Xp + (size_t)c * D_OUT + lane * 4);
        acc.x += v.x; acc.y += v.y; acc.z += v.z; acc.w += v.w;
    }
    *(float4*)(out + (size_t)node * D_OUT + lane * 4) = acc;
}

extern "C" void kernel_launch(void* const* d_in, const int* in_sizes, int n_in,
                              void* d_out, int out_size, void* d_ws, size_t ws_size,
                              hipStream_t stream) {
    const float* X    = (const float*)d_in[0];
    const float* W    = (const float*)d_in[1];
    const int*   rowp = (const int*)d_in[2];
    const int*   colx = (const int*)d_in[3];
    float*       out  = (float*)d_out;
    float*       Xp   = (float*)d_ws;    // n * D_OUT fp32 = 25.6 MB scratch

    const int n = in_sizes[0] / D_IN;    // 50000

    gemm_xw<<<dim3((n + BM - 1) / BM), dim3(256), 0, stream>>>(X, W, Xp, n);
    spmm_agg<<<dim3((n + 7) / 8), dim3(256), 0, stream>>>(Xp, rowp, colx, out, n);
}

// Round 2
// 176.220 us; speedup vs baseline: 1.1893x; 1.1893x over previous
//
#include <hip/hip_runtime.h>

// GCNConv: out = A @ (X @ W)
// Stage 0: W_T[n][k] = bf16(W[k][n])                       (prep kernel, d_ws)
// Stage 1: Xp_bf16 = bf16(X @ W)   via bf16 MFMA 16x16x32  (d_ws)
// Stage 2: out[i,:] = sum_{e} Xp[colx[e],:]   fp32 accumulate

constexpr int D_IN  = 256;
constexpr int D_OUT = 128;
constexpr int BM = 128;
constexpr int BK = 32;
constexpr int LDA = BK + 8;   // padded stride in shorts (40) -> conflict-free-ish

using short8  = __attribute__((ext_vector_type(8))) short;
using float4v = __attribute__((ext_vector_type(4))) float;

__device__ inline ushort f2bf(float f) {
    unsigned u = __float_as_uint(f);
    u = (u + 0x7FFFu + ((u >> 16) & 1u)) >> 16;   // RNE
    return (ushort)u;
}

// W[k][n] fp32 -> W_T[n][k] bf16  (128 rows x 256 cols)
__global__ __launch_bounds__(256) void prep_wt(const float* __restrict__ W,
                                               ushort* __restrict__ WT) {
    int id = blockIdx.x * 256 + threadIdx.x;   // 32768 total
    int nn = id >> 8;        // 0..127
    int k  = id & 255;       // 0..255
    WT[nn * 256 + k] = f2bf(W[k * D_OUT + nn]);
}

__global__ __launch_bounds__(256) void gemm_xw(const float* __restrict__ X,
                                               const ushort* __restrict__ WT,
                                               ushort* __restrict__ Xp, int n) {
    __shared__ ushort Asl[BM * LDA];     // 10 KB
    __shared__ ushort Bsl[D_OUT * LDA];  // 10 KB
    const int tid  = threadIdx.x;
    const int wave = tid >> 6;
    const int lane = tid & 63;
    const int quad = lane >> 4;
    const int l16  = lane & 15;
    const int row0 = blockIdx.x * BM;

    float4v acc[2][8];
#pragma unroll
    for (int i = 0; i < 2; ++i)
#pragma unroll
        for (int t = 0; t < 8; ++t) acc[i][t] = (float4v){0.f, 0.f, 0.f, 0.f};

    for (int k0 = 0; k0 < D_IN; k0 += BK) {
        // Stage A: 128x32 fp32 -> bf16 LDS. 1024 float4, 4 per thread.
#pragma unroll
        for (int i = 0; i < 4; ++i) {
            int idx = i * 256 + tid;
            int r = idx >> 3;        // 8 float4 per 32-float row
            int c4 = idx & 7;
            float4 v = make_float4(0.f, 0.f, 0.f, 0.f);
            if (row0 + r < n)
                v = *(const float4*)(X + (size_t)(row0 + r) * D_IN + k0 + c4 * 4);
            uint2 p;
            p.x = (uint)f2bf(v.x) | ((uint)f2bf(v.y) << 16);
            p.y = (uint)f2bf(v.z) | ((uint)f2bf(v.w) << 16);
            *(uint2*)(&Asl[r * LDA + c4 * 4]) = p;   // 8B aligned (80r + 8c4)
        }
        // Stage B: W_T rows 0..127, k0..k0+31. 512 short8 chunks, 2 per thread.
#pragma unroll
        for (int i = 0; i < 2; ++i) {
            int idx = i * 256 + tid;
            int r  = idx >> 2;       // 4 chunks of 8 shorts per 32-short row
            int ch = idx & 3;
            short8 v = *(const short8*)(WT + r * 256 + k0 + ch * 8);
            *(short8*)(&Bsl[r * LDA + ch * 8]) = v;  // 16B aligned (80r + 16ch)
        }
        __syncthreads();

        // A fragments: lane holds A[m = l16][k = quad*8 + j], rows wave*32 + rt*16
        short8 a0 = *(const short8*)(&Asl[(wave * 32 +      l16) * LDA + quad * 8]);
        short8 a1 = *(const short8*)(&Asl[(wave * 32 + 16 + l16) * LDA + quad * 8]);
#pragma unroll
        for (int t = 0; t < 8; ++t) {
            // B fragment: lane holds B[k = quad*8 + j][nn = t*16 + l16]
            short8 b = *(const short8*)(&Bsl[(t * 16 + l16) * LDA + quad * 8]);
            acc[0][t] = __builtin_amdgcn_mfma_f32_16x16x32_bf16(a0, b, acc[0][t], 0, 0, 0);
            acc[1][t] = __builtin_amdgcn_mfma_f32_16x16x32_bf16(a1, b, acc[1][t], 0, 0, 0);
        }
        __syncthreads();
    }

    // Epilogue: C/D layout col = l16, row = quad*4 + reg
#pragma unroll
    for (int rt = 0; rt < 2; ++rt) {
#pragma unroll
        for (int t = 0; t < 8; ++t) {
#pragma unroll
            for (int r = 0; r < 4; ++r) {
                int row = row0 + wave * 32 + rt * 16 + quad * 4 + r;
                if (row < n)
                    Xp[(size_t)row * D_OUT + t * 16 + l16] = f2bf(acc[rt][t][r]);
            }
        }
    }
}

// One wave per node; lane covers 2 of 128 cols (4B bf16x2 per edge, coalesced).
__global__ __launch_bounds__(256) void spmm_agg(const ushort* __restrict__ Xp,
                                                const int* __restrict__ rowp,
                                                const int* __restrict__ colx,
                                                float* __restrict__ out, int n) {
    const int node = blockIdx.x * 4 + (threadIdx.x >> 6);
    const int lane = threadIdx.x & 63;
    if (node >= n) return;
    const int e0 = rowp[node];
    const int e1 = rowp[node + 1];
    float a0 = 0.f, a1 = 0.f, b0 = 0.f, b1 = 0.f;
    int e = e0;
    for (; e + 1 < e1; e += 2) {
        int c0 = colx[e];
        int c1 = colx[e + 1];
        uint v0 = *(const uint*)(Xp + (size_t)c0 * D_OUT + lane * 2);
        uint v1 = *(const uint*)(Xp + (size_t)c1 * D_OUT + lane * 2);
        a0 += __uint_as_float(v0 << 16);
        a1 += __uint_as_float(v0 & 0xFFFF0000u);
        b0 += __uint_as_float(v1 << 16);
        b1 += __uint_as_float(v1 & 0xFFFF0000u);
    }
    for (; e < e1; ++e) {
        int c = colx[e];
        uint v = *(const uint*)(Xp + (size_t)c * D_OUT + lane * 2);
        a0 += __uint_as_float(v << 16);
        a1 += __uint_as_float(v & 0xFFFF0000u);
    }
    float2 r;
    r.x = a0 + b0;
    r.y = a1 + b1;
    *(float2*)(out + (size_t)node * D_OUT + lane * 2) = r;
}

extern "C" void kernel_launch(void* const* d_in, const int* in_sizes, int n_in,
                              void* d_out, int out_size, void* d_ws, size_t ws_size,
                              hipStream_t stream) {
    const float* X    = (const float*)d_in[0];
    const float* W    = (const float*)d_in[1];
    const int*   rowp = (const int*)d_in[2];
    const int*   colx = (const int*)d_in[3];
    float*       out  = (float*)d_out;

    ushort* WT = (ushort*)d_ws;                       // 128*256*2 = 64 KB
    ushort* Xp = (ushort*)((char*)d_ws + 65536);      // n*128*2 = 12.8 MB

    const int n = in_sizes[0] / D_IN;                 // 50000

    prep_wt<<<dim3(128), dim3(256), 0, stream>>>(W, WT);
    gemm_xw<<<dim3((n + BM - 1) / BM), dim3(256), 0, stream>>>(X, WT, Xp, n);
    spmm_agg<<<dim3((n + 3) / 4), dim3(256), 0, stream>>>(Xp, rowp, colx, out, n);
}

// Round 3
// 145.433 us; speedup vs baseline: 1.4411x; 1.2117x over previous
//
#include <hip/hip_runtime.h>
#include <hip/hip_bf16.h>

// GCNConv: out = A @ (X @ W)
// Stage 0: W_T[n][k] = bf16(W[k][n])                       (prep kernel, d_ws)
// Stage 1: Xp_bf16 = bf16(X @ W)   via bf16 MFMA 16x16x32  (d_ws)
// Stage 2: out[i,:] = sum_{e} Xp[colx[e],:]   fp32 accumulate, 16-deep MLP

constexpr int D_IN  = 256;
constexpr int D_OUT = 128;
constexpr int BM = 128;
constexpr int BK = 32;
constexpr int LDA = BK + 8;   // padded stride in shorts (40)

using short8  = __attribute__((ext_vector_type(8))) short;
using float4v = __attribute__((ext_vector_type(4))) float;

__device__ inline ushort f2bf(float f) {
    unsigned u = __float_as_uint(f);
    u = (u + 0x7FFFu + ((u >> 16) & 1u)) >> 16;   // RNE
    return (ushort)u;
}

__device__ inline uint pk2bf(float lo, float hi) {
    float2 t; t.x = lo; t.y = hi;
    __hip_bfloat162 b = __float22bfloat162_rn(t);   // v_cvt_pk_bf16_f32
    return *(uint*)&b;
}

// W[k][n] fp32 -> W_T[n][k] bf16  (128 rows x 256 cols)
__global__ __launch_bounds__(256) void prep_wt(const float* __restrict__ W,
                                               ushort* __restrict__ WT) {
    int id = blockIdx.x * 256 + threadIdx.x;   // 32768 total
    int nn = id >> 8;        // 0..127
    int k  = id & 255;       // 0..255
    WT[nn * 256 + k] = f2bf(W[k * D_OUT + nn]);
}

__global__ __launch_bounds__(256) void gemm_xw(const float* __restrict__ X,
                                               const ushort* __restrict__ WT,
                                               ushort* __restrict__ Xp, int n) {
    __shared__ ushort Asl[BM * LDA];     // 10 KB
    __shared__ ushort Bsl[D_OUT * LDA];  // 10 KB
    const int tid  = threadIdx.x;
    const int wave = tid >> 6;
    const int lane = tid & 63;
    const int quad = lane >> 4;
    const int l16  = lane & 15;
    const int row0 = blockIdx.x * BM;

    float4v acc[2][8];
#pragma unroll
    for (int i = 0; i < 2; ++i)
#pragma unroll
        for (int t = 0; t < 8; ++t) acc[i][t] = (float4v){0.f, 0.f, 0.f, 0.f};

    for (int k0 = 0; k0 < D_IN; k0 += BK) {
        // Stage A: 128x32 fp32 -> bf16 LDS. 1024 float4, 4 per thread.
#pragma unroll
        for (int i = 0; i < 4; ++i) {
            int idx = i * 256 + tid;
            int r = idx >> 3;        // 8 float4 per 32-float row
            int c4 = idx & 7;
            int row = row0 + r; if (row > n - 1) row = n - 1;   // clamp, no branch
            float4 v = *(const float4*)(X + (size_t)row * D_IN + k0 + c4 * 4);
            uint2 p;
            p.x = pk2bf(v.x, v.y);
            p.y = pk2bf(v.z, v.w);
            *(uint2*)(&Asl[r * LDA + c4 * 4]) = p;   // 8B aligned (80r + 8c4)
        }
        // Stage B: W_T rows 0..127, k0..k0+31. 512 short8 chunks, 2 per thread.
#pragma unroll
        for (int i = 0; i < 2; ++i) {
            int idx = i * 256 + tid;
            int r  = idx >> 2;       // 4 chunks of 8 shorts per 32-short row
            int ch = idx & 3;
            short8 v = *(const short8*)(WT + r * 256 + k0 + ch * 8);
            *(short8*)(&Bsl[r * LDA + ch * 8]) = v;  // 16B aligned (80r + 16ch)
        }
        __syncthreads();

        // A fragments: lane holds A[m = l16][k = quad*8 + j], rows wave*32 + rt*16
        short8 a0 = *(const short8*)(&Asl[(wave * 32 +      l16) * LDA + quad * 8]);
        short8 a1 = *(const short8*)(&Asl[(wave * 32 + 16 + l16) * LDA + quad * 8]);
#pragma unroll
        for (int t = 0; t < 8; ++t) {
            // B fragment: lane holds B[k = quad*8 + j][nn = t*16 + l16]
            short8 b = *(const short8*)(&Bsl[(t * 16 + l16) * LDA + quad * 8]);
            acc[0][t] = __builtin_amdgcn_mfma_f32_16x16x32_bf16(a0, b, acc[0][t], 0, 0, 0);
            acc[1][t] = __builtin_amdgcn_mfma_f32_16x16x32_bf16(a1, b, acc[1][t], 0, 0, 0);
        }
        __syncthreads();
    }

    // Epilogue: C/D layout col = l16, row = quad*4 + reg
#pragma unroll
    for (int rt = 0; rt < 2; ++rt) {
#pragma unroll
        for (int t = 0; t < 8; ++t) {
#pragma unroll
            for (int r = 0; r < 4; ++r) {
                int row = row0 + wave * 32 + rt * 16 + quad * 4 + r;
                if (row < n)
                    Xp[(size_t)row * D_OUT + t * 16 + l16] = f2bf(acc[rt][t][r]);
            }
        }
    }
}

// One wave per node; lane covers 2 of 128 cols (4B bf16x2 per edge, coalesced).
// Degree-16 fast path: 16 index loads, then 16 gathers all in flight.
__global__ __launch_bounds__(256) void spmm_agg(const ushort* __restrict__ Xp,
                                                const int* __restrict__ rowp,
                                                const int* __restrict__ colx,
                                                float* __restrict__ out, int n) {
    const int node = blockIdx.x * 4 + (threadIdx.x >> 6);
    const int lane = threadIdx.x & 63;
    if (node >= n) return;
    const int e0 = rowp[node];
    const int e1 = rowp[node + 1];
    const ushort* src = Xp + lane * 2;
    float s0 = 0.f, s1 = 0.f;
    if (e1 - e0 == 16) {
        int c[16];
#pragma unroll
        for (int i = 0; i < 16; ++i) c[i] = colx[e0 + i];   // wave-uniform -> s_load
        uint v[16];
#pragma unroll
        for (int i = 0; i < 16; ++i)
            v[i] = *(const uint*)(src + (size_t)c[i] * D_OUT);  // 16 gathers in flight
#pragma unroll
        for (int i = 0; i < 16; ++i) {
            s0 += __uint_as_float(v[i] << 16);
            s1 += __uint_as_float(v[i] & 0xFFFF0000u);
        }
    } else {
        for (int e = e0; e < e1; ++e) {
            uint v = *(const uint*)(src + (size_t)colx[e] * D_OUT);
            s0 += __uint_as_float(v << 16);
            s1 += __uint_as_float(v & 0xFFFF0000u);
        }
    }
    float2 r; r.x = s0; r.y = s1;
    *(float2*)(out + (size_t)node * D_OUT + lane * 2) = r;
}

extern "C" void kernel_launch(void* const* d_in, const int* in_sizes, int n_in,
                              void* d_out, int out_size, void* d_ws, size_t ws_size,
                              hipStream_t stream) {
    const float* X    = (const float*)d_in[0];
    const float* W    = (const float*)d_in[1];
    const int*   rowp = (const int*)d_in[2];
    const int*   colx = (const int*)d_in[3];
    float*       out  = (float*)d_out;

    ushort* WT = (ushort*)d_ws;                       // 128*256*2 = 64 KB
    ushort* Xp = (ushort*)((char*)d_ws + 65536);      // n*128*2 = 12.8 MB

    const int n = in_sizes[0] / D_IN;                 // 50000

    prep_wt<<<dim3(128), dim3(256), 0, stream>>>(W, WT);
    gemm_xw<<<dim3((n + BM - 1) / BM), dim3(256), 0, stream>>>(X, WT, Xp, n);
    spmm_agg<<<dim3((n + 3) / 4), dim3(256), 0, stream>>>(Xp, rowp, colx, out, n);
}